// Round 1
// baseline (319.964 us; speedup 1.0000x reference)
//
#include <hip/hip_runtime.h>

// BasicBlock: y = relu(bn2(conv2(relu(bn1(conv1(x, we1))), we2)) + x)
// where we{1,2} = sum_e alpha[e] * w{1,2}[e]  (conv linear in weights).
//
// Strategy: bf16 implicit-GEMM conv with mfma_f32_16x16x32_bf16.
//   prep:   fold experts -> w_eff bf16 [kpos][o][i], fold BN -> inv/bias
//   pass 0: conv1 + bn1 + relu -> y1 (NHWC bf16, in workspace)
//   pass 1: conv2 + bn2 + residual(x fp32) + relu -> out (NCHW fp32)
// Each workgroup: 8x16 pixel tile x 64 outch, K=576 consumed from ONE
// LDS-staged input tile (10x18x64ch, halo zero-filled, 144B pixel stride
// to dodge bank conflicts on the stride-128B A-fragment reads).

typedef __bf16 bf16x8 __attribute__((ext_vector_type(8)));
typedef float f32x4 __attribute__((ext_vector_type(4)));
typedef unsigned short u16;
typedef u16 u16x8 __attribute__((ext_vector_type(8)));

#define NB 32
#define NC 64
#define NH 112
#define NW 112

__device__ __forceinline__ u16 f2b(float f) {
  // round-to-nearest-even fp32 -> bf16 (finite inputs only)
  unsigned u = __builtin_bit_cast(unsigned, f);
  u += 0x7FFFu + ((u >> 16) & 1u);
  return (u16)(u >> 16);
}

// ---------------------------------------------------------------------------
// prep: w_eff[kpos][o][i] (bf16) for both convs + folded BN constants
// ---------------------------------------------------------------------------
__global__ void prep_kernel(
    const float* __restrict__ w1, const float* __restrict__ w2,
    const float* __restrict__ alpha,
    const float* __restrict__ g1, const float* __restrict__ b1,
    const float* __restrict__ m1, const float* __restrict__ v1,
    const float* __restrict__ g2, const float* __restrict__ b2,
    const float* __restrict__ m2, const float* __restrict__ v2,
    u16* __restrict__ weff1, u16* __restrict__ weff2, float* __restrict__ bnc) {
  int idx = blockIdx.x * 256 + threadIdx.x;  // 9*64*64 = 36864 total
  if (idx < 36864) {
    int i = idx & 63;
    int o = (idx >> 6) & 63;
    int kpos = idx >> 12;  // kh*3+kw
    // src layout [E][O][I][3][3]
    int base = (o * 64 + i) * 9 + kpos;
    float a1 = 0.f, a2 = 0.f;
#pragma unroll
    for (int e = 0; e < 10; ++e) {
      float al = alpha[e];
      a1 += al * w1[e * 36864 + base];
      a2 += al * w2[e * 36864 + base];
    }
    weff1[idx] = f2b(a1);
    weff2[idx] = f2b(a2);
  }
  if (blockIdx.x == 0 && threadIdx.x < 64) {
    int c = threadIdx.x;
    float i1 = g1[c] * rsqrtf(v1[c] + 1e-5f);
    float i2 = g2[c] * rsqrtf(v2[c] + 1e-5f);
    bnc[c] = i1;
    bnc[64 + c] = b1[c] - m1[c] * i1;
    bnc[128 + c] = i2;
    bnc[192 + c] = b2[c] - m2[c] * i2;
  }
}

// ---------------------------------------------------------------------------
// conv pass. PASS 0: x(NCHW f32) -> y1(NHWC bf16).  PASS 1: y1 -> out(NCHW f32)
// Tile: 8 rows x 16 cols of pixels, all 64 output channels.
// grid = 32 b * 14 htiles * 7 wtiles = 3136 blocks, 256 threads (4 waves).
// ---------------------------------------------------------------------------
#define PIXSTRIDE 144  // bytes per (row,col) pixel block in LDS (128B + 16B pad)

template <int PASS>
__global__ void conv_bn_kernel(const float* __restrict__ x,
                               const u16* __restrict__ yin,
                               const u16* __restrict__ weff,
                               const float* __restrict__ bnc,
                               u16* __restrict__ yout,
                               float* __restrict__ out) {
  __shared__ alignas(16) char smem[33792];

  int tid = threadIdx.x;
  int lane = tid & 63;
  int wv = tid >> 6;
  int bid = blockIdx.x;
  int b = bid / 98;
  int r = bid % 98;
  int h0 = (r / 7) * 8;
  int w0 = (r % 7) * 16;

  // ---- stage input tile: rows h0-1..h0+8, cols w0-1..w0+16, 64 ch ----
  if constexpr (PASS == 0) {
    // from NCHW fp32: per (row,ch), 6 aligned float4 covering w0-4..w0+19
    for (int it = 0; it < 15; ++it) {
      int fid = it * 256 + tid;  // 0..3839 = 10*64*6
      int q = fid % 6;
      int rc = fid / 6;
      int ch = rc & 63;
      int row = rc >> 6;
      int h = h0 - 1 + row;
      int wb = w0 - 4 + q * 4;
      f32x4 v = {0.f, 0.f, 0.f, 0.f};
      if ((unsigned)h < (unsigned)NH && (unsigned)wb <= 108u)
        v = *reinterpret_cast<const f32x4*>(x + (((b * NC + ch) * NH + h) * NW + wb));
#pragma unroll
      for (int j = 0; j < 4; ++j) {
        int col = wb + j - (w0 - 1);
        if ((unsigned)col < 18u)
          *reinterpret_cast<u16*>(smem + (row * 18 + col) * PIXSTRIDE + ch * 2) = f2b(v[j]);
      }
    }
  } else {
    // from NHWC bf16: 16B chunks, fully coalesced (rows are 2304B contiguous)
    for (int it = 0; it < 6; ++it) {
      int cidx = it * 256 + tid;
      if (cidx < 1440) {  // 10*18*8
        int c8 = cidx & 7;
        int pc = cidx >> 3;
        int col = pc % 18;
        int row = pc / 18;
        int h = h0 - 1 + row, w = w0 - 1 + col;
        u16x8 v = {0, 0, 0, 0, 0, 0, 0, 0};
        if ((unsigned)h < (unsigned)NH && (unsigned)w < (unsigned)NW)
          v = *reinterpret_cast<const u16x8*>(yin + (((b * NH + h) * NW + w) << 6) + c8 * 8);
        *reinterpret_cast<u16x8*>(smem + (row * 18 + col) * PIXSTRIDE + c8 * 16) = v;
      }
    }
  }
  __syncthreads();

  // ---- MFMA main: 9 kernel positions x 2 k-steps, acc 2 Mfrags x 4 Nfrags ----
  f32x4 acc[2][4];
#pragma unroll
  for (int mf = 0; mf < 2; ++mf)
#pragma unroll
    for (int nf = 0; nf < 4; ++nf) acc[mf][nf] = f32x4{0.f, 0.f, 0.f, 0.f};

  int ol = lane & 15;  // A: pixel col in frag / B,D: outch in frag
  int kg = lane >> 4;  // k-group (8 contiguous k per lane)
  int f0 = wv * 2;     // this wave's first Mfrag (= tile row)

#pragma unroll
  for (int kh = 0; kh < 3; ++kh)
#pragma unroll
    for (int kw = 0; kw < 3; ++kw) {
      int kpos = kh * 3 + kw;
      bf16x8 bf[2][4];
#pragma unroll
      for (int ks = 0; ks < 2; ++ks)
#pragma unroll
        for (int nf = 0; nf < 4; ++nf) {
          const u16* p = weff + ((kpos * 64 + nf * 16 + ol) * 64 + ks * 32 + kg * 8);
          bf[ks][nf] = __builtin_bit_cast(bf16x8, *reinterpret_cast<const u16x8*>(p));
        }
#pragma unroll
      for (int ks = 0; ks < 2; ++ks)
#pragma unroll
        for (int mf = 0; mf < 2; ++mf) {
          int off = ((f0 + mf + kh) * 18 + ol + kw) * PIXSTRIDE + ks * 64 + kg * 16;
          bf16x8 af = *reinterpret_cast<const bf16x8*>(smem + off);
#pragma unroll
          for (int nf = 0; nf < 4; ++nf)
            acc[mf][nf] = __builtin_amdgcn_mfma_f32_16x16x32_bf16(af, bf[ks][nf], acc[mf][nf], 0, 0, 0);
        }
    }

  // ---- epilogue ----
  float inv[4], bias[4];
#pragma unroll
  for (int nf = 0; nf < 4; ++nf) {
    int o = nf * 16 + ol;
    inv[nf] = bnc[PASS * 128 + o];
    bias[nf] = bnc[PASS * 128 + 64 + o];
  }
  __syncthreads();  // done reading A tile; reuse LDS

  if constexpr (PASS == 0) {
    // bn1+relu -> bf16, transpose through LDS -> coalesced NHWC store
    u16* ys = reinterpret_cast<u16*>(smem);  // [128 px][64 ch]
#pragma unroll
    for (int mf = 0; mf < 2; ++mf)
#pragma unroll
      for (int nf = 0; nf < 4; ++nf) {
        int o = nf * 16 + ol;
#pragma unroll
        for (int rg = 0; rg < 4; ++rg) {
          int p = (f0 + mf) * 16 + kg * 4 + rg;
          float v = fmaxf(acc[mf][nf][rg] * inv[nf] + bias[nf], 0.f);
          ys[p * 64 + o] = f2b(v);
        }
      }
    __syncthreads();
#pragma unroll
    for (int it = 0; it < 4; ++it) {
      int cidx = it * 256 + tid;  // 0..1023
      int c8 = cidx & 7, p = cidx >> 3;
      int h = h0 + (p >> 4), w = w0 + (p & 15);
      *reinterpret_cast<u16x8*>(yout + (((b * NH + h) * NW + w) << 6) + c8 * 8) =
          *reinterpret_cast<const u16x8*>(ys + p * 64 + c8 * 8);
    }
  } else {
    // bn2 -> LDS transpose [o][128+pad px] f32 -> +residual, relu, NCHW store
#pragma unroll
    for (int mf = 0; mf < 2; ++mf)
#pragma unroll
      for (int nf = 0; nf < 4; ++nf) {
        int o = nf * 16 + ol;
        int p0 = (f0 + mf) * 16 + kg * 4;
        f32x4 v;
#pragma unroll
        for (int rg = 0; rg < 4; ++rg) v[rg] = acc[mf][nf][rg] * inv[nf] + bias[nf];
        *reinterpret_cast<f32x4*>(smem + o * 528 + p0 * 4) = v;  // 132 f32 row stride
      }
    __syncthreads();
#pragma unroll
    for (int it = 0; it < 8; ++it) {
      int cidx = it * 256 + tid;  // 0..2047
      int g = cidx & 31, o = cidx >> 5;
      f32x4 v = *reinterpret_cast<const f32x4*>(smem + o * 528 + g * 16);
      int p = g * 4;
      int h = h0 + (p >> 4), w = w0 + (p & 15);
      int gi = ((b * NC + o) * NH + h) * NW + w;
      f32x4 xr = *reinterpret_cast<const f32x4*>(x + gi);
#pragma unroll
      for (int rg = 0; rg < 4; ++rg) v[rg] = fmaxf(v[rg] + xr[rg], 0.f);
      *reinterpret_cast<f32x4*>(out + gi) = v;
    }
  }
}

// ---------------------------------------------------------------------------
extern "C" void kernel_launch(void* const* d_in, const int* in_sizes, int n_in,
                              void* d_out, int out_size, void* d_ws, size_t ws_size,
                              hipStream_t stream) {
  const float* x = (const float*)d_in[0];
  const float* w1 = (const float*)d_in[1];
  const float* w2 = (const float*)d_in[2];
  const float* alpha = (const float*)d_in[3];
  const float* g1 = (const float*)d_in[4];
  const float* b1 = (const float*)d_in[5];
  const float* m1 = (const float*)d_in[6];
  const float* v1 = (const float*)d_in[7];
  const float* g2 = (const float*)d_in[8];
  const float* b2 = (const float*)d_in[9];
  const float* m2 = (const float*)d_in[10];
  const float* v2 = (const float*)d_in[11];
  float* out = (float*)d_out;

  char* ws = (char*)d_ws;
  u16* weff1 = (u16*)ws;                    // 73728 B
  u16* weff2 = (u16*)(ws + 73728);          // 73728 B
  float* bnc = (float*)(ws + 147456);       // 1024 B
  u16* y1 = (u16*)(ws + 148480);            // 32*112*112*64*2 = 51380224 B

  prep_kernel<<<144, 256, 0, stream>>>(w1, w2, alpha, g1, b1, m1, v1,
                                       g2, b2, m2, v2, weff1, weff2, bnc);
  conv_bn_kernel<0><<<3136, 256, 0, stream>>>(x, nullptr, weff1, bnc, y1, nullptr);
  conv_bn_kernel<1><<<3136, 256, 0, stream>>>(x, y1, weff2, bnc, nullptr, out);
}